// Round 7
// baseline (122.997 us; speedup 1.0000x reference)
//
#include <hip/hip_runtime.h>
#include <math.h>

#define NB 65536          // batch
#define NBLK1 1024        // fused grid: NB / IMGS1
#define IMGS1 64          // images per block
#define F4_PER_IMG 196    // 784 floats = 196 float4 per image
#define F4_PER_BLK (IMGS1 * F4_PER_IMG)   // 12544
#define ITERS (F4_PER_BLK / 256)          // 49
#define ACC_STRIDE 17     // padded: 16 windows + 1 (also absorbs q=6 guard)

// ---------------------------------------------------------------------------
// Fused kernel: W-build (wave 3 lanes 0-15) + contiguous-stream avg-pool +
// pre-FC + quantum matvec + logits + per-block BN partials.
// Pool: block owns 64 contiguous images; lanes stream contiguous float4s
// (16 cache lines per load instruction) and scatter window partial sums
// into LDS via branch-free dual atomicAdd.
// ---------------------------------------------------------------------------
__global__ __launch_bounds__(256) void fused_kernel(
        const float* __restrict__ x,        // [B][1][28][28]
        const float* __restrict__ pre_w,    // [4][16]
        const float* __restrict__ pre_b,    // [4]
        const float* __restrict__ weights,  // [3][4][2]
        const float* __restrict__ fc_w,     // [4][4]
        const float* __restrict__ fc_b,     // [4]
        float4* __restrict__ out,           // [B] raw logits
        float* __restrict__ partial) {      // [NBLK1][8]
    __shared__ float2 Wl[256];
    __shared__ float acc[IMGS1][ACC_STRIDE];   // 64*17*4 = 4352 B
    const int tid = threadIdx.x;

    // ---------------- zero window accumulators -----------------------------
#pragma unroll
    for (int i = 0; i < (IMGS1 * ACC_STRIDE + 255) / 256; ++i) {
        int idx = i * 256 + tid;
        if (idx < IMGS1 * ACC_STRIDE) ((float*)acc)[idx] = 0.f;
    }
    __syncthreads();

    // ---------------- build W on wave 3 lanes 0-15 -------------------------
    // (hidden under waves 0-2's streaming; needed only after the barrier)
    if (tid >= 192 && tid < 208) {
        const int t = tid - 192;
        float cr[16], ci[16];
#pragma unroll
        for (int i = 0; i < 16; ++i) { cr[i] = (i == t) ? 1.0f : 0.0f; ci[i] = 0.0f; }

        for (int l = 0; l < 3; ++l) {
#pragma unroll
            for (int w = 0; w < 4; ++w) {
                const int mask = 8 >> w;            // wire w -> bit (3-w)
                float tx = weights[(l * 4 + w) * 2 + 0] * 0.5f;
                float c = cosf(tx), s = sinf(tx);
#pragma unroll
                for (int i = 0; i < 16; ++i) {
                    if (!(i & mask)) {
                        const int ip = i | mask;
                        float a0r = cr[i], a0i = ci[i], a1r = cr[ip], a1i = ci[ip];
                        cr[i]  = c * a0r + s * a1i;   // [[c,-is],[-is,c]]
                        ci[i]  = c * a0i - s * a1r;
                        cr[ip] = c * a1r + s * a0i;
                        ci[ip] = c * a1i - s * a0r;
                    }
                }
                float tz = weights[(l * 4 + w) * 2 + 1] * 0.5f;
                float ce = cosf(tz), se = sinf(tz);
#pragma unroll
                for (int i = 0; i < 16; ++i) {
                    if (!(i & mask)) {
                        const int ip = i | mask;
                        float a0r = cr[i], a0i = ci[i], a1r = cr[ip], a1i = ci[ip];
                        cr[i]  = ce * a0r + se * a0i;  // e^{-i tz}
                        ci[i]  = ce * a0i - se * a0r;
                        cr[ip] = ce * a1r - se * a1i;  // e^{+i tz}
                        ci[ip] = ce * a1i + se * a1r;
                    }
                }
            }
#pragma unroll
            for (int w = 0; w < 4; ++w) {           // CNOT ring
                const int mc = 8 >> w;
                const int mt = 8 >> ((w + 1) & 3);
#pragma unroll
                for (int i = 0; i < 16; ++i) {
                    if ((i & mc) && !(i & mt)) {
                        const int ip = i | mt;
                        float tr = cr[i], ti = ci[i];
                        cr[i] = cr[ip]; ci[i] = ci[ip];
                        cr[ip] = tr;   ci[ip] = ti;
                    }
                }
            }
        }
        int p = __popc(t) & 3;   // fold zeta_j = (-i)^popcount(j)
#pragma unroll
        for (int i = 0; i < 16; ++i) {
            float wr, wi;
            if (p == 0)      { wr =  cr[i]; wi =  ci[i]; }
            else if (p == 1) { wr =  ci[i]; wi = -cr[i]; }
            else if (p == 2) { wr = -cr[i]; wi = -ci[i]; }
            else             { wr = -ci[i]; wi =  cr[i]; }
            Wl[i * 16 + t] = make_float2(wr, wi);
        }
    }

    // ---------------- contiguous-stream pooling ----------------------------
    // lane reads f4[k*256+tid]: one contiguous 1 KB per wave instruction.
    const float4* xin = (const float4*)x + (size_t)blockIdx.x * F4_PER_BLK;
#pragma unroll 7
    for (int k = 0; k < ITERS; ++k) {
        const int idx = k * 256 + tid;          // 0 .. 12543
        float4 v = xin[idx];
        const int img = idx / F4_PER_IMG;       // const-div -> mulhi
        const int rem = idx - img * F4_PER_IMG;
        const int row = rem / 7;
        const int q   = rem - row * 7;
        if (row < 24 && q < 6) {
            const int band = row / 6;            // vertical window 0..3
            float* a = &acc[img][band * 4];
            const int lo = (q * 4) / 6;          // window of cols 4q,4q+1
            const int hi = (q * 4 + 3) / 6;      // window of cols 4q+2,4q+3
            atomicAdd(&a[lo], v.x + v.y);        // same addr when unsplit --
            atomicAdd(&a[hi], v.z + v.w);        // -- still sums correctly
        }
    }
    __syncthreads();

    // ---------------- quantum matvec + logits (wave 0) ---------------------
    if (tid < IMGS1) {
        // pre-FC from window sums (pre_w reads are wave-uniform -> s_load)
        const float inv36 = 1.0f / 36.0f;
        float e0 = pre_b[0], e1 = pre_b[1], e2 = pre_b[2], e3 = pre_b[3];
#pragma unroll
        for (int k = 0; k < 16; ++k) {
            float a = acc[tid][k] * inv36;       // stride 17 -> conflict-free
            e0 += a * pre_w[k];
            e1 += a * pre_w[16 + k];
            e2 += a * pre_w[32 + k];
            e3 += a * pre_w[48 + k];
        }

        float s0, c0, s1, c1, s2, c2, s3, c3;
        __sincosf(e0 * 0.5f, &s0, &c0);
        __sincosf(e1 * 0.5f, &s1, &c1);
        __sincosf(e2 * 0.5f, &s2, &c2);
        __sincosf(e3 * 0.5f, &s3, &c3);

        float m01[4] = { c0 * c1, c0 * s1, s0 * c1, s0 * s1 };
        float m23[4] = { c2 * c3, c2 * s3, s2 * c3, s2 * s3 };
        float m[16];
#pragma unroll
        for (int i = 0; i < 16; ++i) m[i] = m01[i >> 2] * m23[i & 3];

        float z0 = 0.f, z1 = 0.f, z2 = 0.f, z3 = 0.f;
#pragma unroll
        for (int i = 0; i < 16; ++i) {
            float sr = 0.f, si = 0.f;
#pragma unroll
            for (int j = 0; j < 16; ++j) {
                float2 w = Wl[i * 16 + j];   // wave-uniform -> LDS broadcast
                sr += w.x * m[j];
                si += w.y * m[j];
            }
            float pr = sr * sr + si * si;
            z0 += (i & 8) ? -pr : pr;
            z1 += (i & 4) ? -pr : pr;
            z2 += (i & 2) ? -pr : pr;
            z3 += (i & 1) ? -pr : pr;
        }

        float l0 = fc_b[0] + fc_w[0]  * z0 + fc_w[1]  * z1 + fc_w[2]  * z2 + fc_w[3]  * z3;
        float l1 = fc_b[1] + fc_w[4]  * z0 + fc_w[5]  * z1 + fc_w[6]  * z2 + fc_w[7]  * z3;
        float l2 = fc_b[2] + fc_w[8]  * z0 + fc_w[9]  * z1 + fc_w[10] * z2 + fc_w[11] * z3;
        float l3 = fc_b[3] + fc_w[12] * z0 + fc_w[13] * z1 + fc_w[14] * z2 + fc_w[15] * z3;
        out[(size_t)blockIdx.x * IMGS1 + tid] = make_float4(l0, l1, l2, l3);

        // BN partials over the 64 images (wave 0)
        float s[8] = { l0, l1, l2, l3, l0 * l0, l1 * l1, l2 * l2, l3 * l3 };
#pragma unroll
        for (int off = 32; off; off >>= 1) {
#pragma unroll
            for (int q2 = 0; q2 < 8; ++q2) s[q2] += __shfl_down(s[q2], off);
        }
        if (tid == 0) {
            float4* p = (float4*)(partial + (size_t)blockIdx.x * 8);
            p[0] = make_float4(s[0], s[1], s[2], s[3]);
            p[1] = make_float4(s[4], s[5], s[6], s[7]);
        }
    }
}

// ---------------------------------------------------------------------------
// Finalize: each of 256 blocks redundantly reduces the 1024x8 partials
// (L2-hit), computes scale/shift, normalizes its 256 images in place.
// ---------------------------------------------------------------------------
__global__ __launch_bounds__(256) void finalize_kernel(
        float4* __restrict__ out,
        const float* __restrict__ partial,   // [NBLK1][8]
        const float* __restrict__ gamma,
        const float* __restrict__ beta) {
    __shared__ float red4[4][8];
    __shared__ float scsh[8];
    const int tid = threadIdx.x;

    float s[8];
#pragma unroll
    for (int q = 0; q < 8; ++q) s[q] = 0.f;
#pragma unroll
    for (int r = 0; r < NBLK1 / 256; ++r) {
        const float4* row = (const float4*)(partial + (size_t)(tid + r * 256) * 8);
        float4 a = row[0], c = row[1];
        s[0] += a.x; s[1] += a.y; s[2] += a.z; s[3] += a.w;
        s[4] += c.x; s[5] += c.y; s[6] += c.z; s[7] += c.w;
    }
#pragma unroll
    for (int off = 32; off; off >>= 1) {
#pragma unroll
        for (int q = 0; q < 8; ++q) s[q] += __shfl_down(s[q], off);
    }
    if ((tid & 63) == 0) {
#pragma unroll
        for (int q = 0; q < 8; ++q) red4[tid >> 6][q] = s[q];
    }
    __syncthreads();
    if (tid < 8) {
        red4[0][tid] = red4[0][tid] + red4[1][tid] + red4[2][tid] + red4[3][tid];
    }
    __syncthreads();
    if (tid < 4) {
        const float invB = 1.0f / (float)NB;
        float mean = red4[0][tid] * invB;
        float var  = red4[0][4 + tid] * invB - mean * mean;
        float inv  = rsqrtf(var + 1e-5f);
        float g = gamma[tid];
        scsh[tid]     = g * inv;
        scsh[4 + tid] = beta[tid] - mean * g * inv;
    }
    __syncthreads();

    const float sc0 = scsh[0], sc1 = scsh[1], sc2 = scsh[2], sc3 = scsh[3];
    const float sh0 = scsh[4], sh1 = scsh[5], sh2 = scsh[6], sh3 = scsh[7];
    const int b = blockIdx.x * 256 + tid;    // 256 blocks cover NB
    float4 v = out[b];
    v.x = v.x * sc0 + sh0;
    v.y = v.y * sc1 + sh1;
    v.z = v.z * sc2 + sh2;
    v.w = v.w * sc3 + sh3;
    out[b] = v;
}

// ---------------------------------------------------------------------------
extern "C" void kernel_launch(void* const* d_in, const int* in_sizes, int n_in,
                              void* d_out, int out_size, void* d_ws, size_t ws_size,
                              hipStream_t stream) {
    const float* x       = (const float*)d_in[0];
    const float* pre_w   = (const float*)d_in[1];
    const float* pre_b   = (const float*)d_in[2];
    const float* weights = (const float*)d_in[3];
    const float* fc_w    = (const float*)d_in[4];
    const float* fc_b    = (const float*)d_in[5];
    const float* gamma   = (const float*)d_in[6];
    const float* beta    = (const float*)d_in[7];

    float* partial = (float*)d_ws;           // NBLK1*8*4 = 32 KB

    hipLaunchKernelGGL(fused_kernel, dim3(NBLK1), dim3(256), 0, stream,
                       x, pre_w, pre_b, weights, fc_w, fc_b,
                       (float4*)d_out, partial);
    hipLaunchKernelGGL(finalize_kernel, dim3(NB / 256), dim3(256), 0, stream,
                       (float4*)d_out, partial, gamma, beta);
}

// Round 8
// 46.862 us; speedup vs baseline: 2.6247x; 2.6247x over previous
//
#include <hip/hip_runtime.h>
#include <math.h>

#define NB 65536          // batch
#define NBLK1 1024        // fused grid: NB / IMGS1
#define IMGS1 64          // images per block
#define CHUNK_IMGS 16     // images per staging chunk
#define CHUNK_F4 (CHUNK_IMGS * 196)   // 3136 float4 per chunk

// ---------------------------------------------------------------------------
// Scatter one float4 of the contiguous stream into its unique rws slots.
// idx in [0, 3136) within chunk: img = idx/196, row = rem/7, q = rem%7.
// Window w = col/6; f4 q covers cols 4q..4q+3 -> lo window (2q)/3, split iff
// q%3==1. Slot assignment gives every (img,row<24,w,s) EXACTLY ONE writer:
//   w0s0<-q0, w0s1<-q1lo, w1s0<-q1hi, w1s1<-q2,
//   w2s0<-q3, w2s1<-q4lo, w3s0<-q4hi, w3s1<-q5.
// Plain ds_write (no atomic, no zeroing needed).
// ---------------------------------------------------------------------------
__device__ __forceinline__ void scatter_f4(float4 v, int idx, float* rb) {
    const int img = idx / 196;
    const int rem = idx - img * 196;
    const int row = rem / 7;
    const int q   = rem - row * 7;
    if (row < 24 && q < 6) {
        const bool split = (q == 1) || (q == 4);
        const int wlo = (2 * q) / 3;
        const int slo = (q == 0 || q == 3) ? 0 : 1;
        const float vlo = v.x + v.y + (split ? 0.f : (v.z + v.w));
        float* rp = rb + ((img * 25 + row) * 4 + wlo) * 2;
        rp[slo] = vlo;
        if (split) rp[2] = v.z + v.w;      // (wlo+1, slot 0)
    }
}

// ---------------------------------------------------------------------------
// Fused kernel: W-build (wave 3) + coalesced-stream pool (no atomics) +
// pre-FC + quantum matvec + logits + per-block BN partials.
// ---------------------------------------------------------------------------
__global__ __launch_bounds__(256) void fused_kernel(
        const float* __restrict__ x,        // [B][1][28][28]
        const float* __restrict__ pre_w,    // [4][16]
        const float* __restrict__ pre_b,    // [4]
        const float* __restrict__ weights,  // [3][4][2]
        const float* __restrict__ fc_w,     // [4][4]
        const float* __restrict__ fc_b,     // [4]
        float4* __restrict__ out,           // [B] raw logits
        float* __restrict__ partial) {      // [NBLK1][8]
    __shared__ float rws[2][CHUNK_IMGS][25][4][2];  // 25.6 KB, double-buffered
    __shared__ float2 Wl[256];
    __shared__ float4 enc[IMGS1];
    const int tid = threadIdx.x;

    // ---------------- build W on wave 3 lanes 0-15 -------------------------
    if (tid >= 192 && tid < 208) {
        const int t = tid - 192;
        float cr[16], ci[16];
#pragma unroll
        for (int i = 0; i < 16; ++i) { cr[i] = (i == t) ? 1.0f : 0.0f; ci[i] = 0.0f; }

        for (int l = 0; l < 3; ++l) {
#pragma unroll
            for (int w = 0; w < 4; ++w) {
                const int mask = 8 >> w;            // wire w -> bit (3-w)
                float tx = weights[(l * 4 + w) * 2 + 0] * 0.5f;
                float c = cosf(tx), s = sinf(tx);
#pragma unroll
                for (int i = 0; i < 16; ++i) {
                    if (!(i & mask)) {
                        const int ip = i | mask;
                        float a0r = cr[i], a0i = ci[i], a1r = cr[ip], a1i = ci[ip];
                        cr[i]  = c * a0r + s * a1i;   // [[c,-is],[-is,c]]
                        ci[i]  = c * a0i - s * a1r;
                        cr[ip] = c * a1r + s * a0i;
                        ci[ip] = c * a1i - s * a0r;
                    }
                }
                float tz = weights[(l * 4 + w) * 2 + 1] * 0.5f;
                float ce = cosf(tz), se = sinf(tz);
#pragma unroll
                for (int i = 0; i < 16; ++i) {
                    if (!(i & mask)) {
                        const int ip = i | mask;
                        float a0r = cr[i], a0i = ci[i], a1r = cr[ip], a1i = ci[ip];
                        cr[i]  = ce * a0r + se * a0i;  // e^{-i tz}
                        ci[i]  = ce * a0i - se * a0r;
                        cr[ip] = ce * a1r - se * a1i;  // e^{+i tz}
                        ci[ip] = ce * a1i + se * a1r;
                    }
                }
            }
#pragma unroll
            for (int w = 0; w < 4; ++w) {           // CNOT ring
                const int mc = 8 >> w;
                const int mt = 8 >> ((w + 1) & 3);
#pragma unroll
                for (int i = 0; i < 16; ++i) {
                    if ((i & mc) && !(i & mt)) {
                        const int ip = i | mt;
                        float tr = cr[i], ti = ci[i];
                        cr[i] = cr[ip]; ci[i] = ci[ip];
                        cr[ip] = tr;   ci[ip] = ti;
                    }
                }
            }
        }
        int p = __popc(t) & 3;   // fold zeta_j = (-i)^popcount(j)
#pragma unroll
        for (int i = 0; i < 16; ++i) {
            float wr, wi;
            if (p == 0)      { wr =  cr[i]; wi =  ci[i]; }
            else if (p == 1) { wr =  ci[i]; wi = -cr[i]; }
            else if (p == 2) { wr = -cr[i]; wi = -ci[i]; }
            else             { wr = -ci[i]; wi =  cr[i]; }
            Wl[i * 16 + t] = make_float2(wr, wi);
        }
    }

    // ---------------- pool: 4 chunks of 16 images --------------------------
    const float4* xbase = (const float4*)x + (size_t)blockIdx.x * (IMGS1 * 196);
    const float b0 = pre_b[0], b1 = pre_b[1], b2 = pre_b[2], b3 = pre_b[3];

    for (int c = 0; c < 4; ++c) {
        float* rb = &rws[c & 1][0][0][0][0];
        const float4* xc = xbase + c * CHUNK_F4;

        // coalesced stream: lane reads f4[k*256+tid] (contiguous per instr)
#pragma unroll
        for (int k = 0; k < 12; ++k) {
            const int idx = k * 256 + tid;
            scatter_f4(xc[idx], idx, rb);
        }
        if (tid < 64) scatter_f4(xc[3072 + tid], 3072 + tid, rb);
        __syncthreads();

        // reduce: thread = (img, w); 12 slot reads (2-way conflicts = free)
        {
            const int img = tid >> 4, w = tid & 15;
            const int band = w >> 2, cw = w & 3;
            float ws = 0.f;
#pragma unroll
            for (int r = 0; r < 6; ++r) {
                const float* rp = rb + ((img * 25 + band * 6 + r) * 4 + cw) * 2;
                ws += rp[0] + rp[1];
            }
            ws *= (1.0f / 36.0f);
            float p0 = ws * pre_w[w];
            float p1 = ws * pre_w[16 + w];
            float p2 = ws * pre_w[32 + w];
            float p3 = ws * pre_w[48 + w];
#pragma unroll
            for (int off = 1; off < 16; off <<= 1) {
                p0 += __shfl_xor(p0, off);
                p1 += __shfl_xor(p1, off);
                p2 += __shfl_xor(p2, off);
                p3 += __shfl_xor(p3, off);
            }
            if (w == 0) {
                enc[c * 16 + img] = make_float4(p0 + b0, p1 + b1, p2 + b2, p3 + b3);
            }
        }
        // no barrier here: next chunk scatters into the other buffer; the
        // barrier inside chunk c+1 orders R2(c) before scatter(c+2).
    }
    __syncthreads();

    // ---------------- quantum matvec + logits (wave 0) ---------------------
    if (tid < IMGS1) {
        float4 e = enc[tid];
        float s0, c0, s1, c1, s2, c2, s3, c3;
        __sincosf(e.x * 0.5f, &s0, &c0);
        __sincosf(e.y * 0.5f, &s1, &c1);
        __sincosf(e.z * 0.5f, &s2, &c2);
        __sincosf(e.w * 0.5f, &s3, &c3);

        float m01[4] = { c0 * c1, c0 * s1, s0 * c1, s0 * s1 };
        float m23[4] = { c2 * c3, c2 * s3, s2 * c3, s2 * s3 };
        float m[16];
#pragma unroll
        for (int i = 0; i < 16; ++i) m[i] = m01[i >> 2] * m23[i & 3];

        float z0 = 0.f, z1 = 0.f, z2 = 0.f, z3 = 0.f;
#pragma unroll
        for (int i = 0; i < 16; ++i) {
            float sr = 0.f, si = 0.f;
#pragma unroll
            for (int j = 0; j < 16; ++j) {
                float2 w = Wl[i * 16 + j];   // wave-uniform -> LDS broadcast
                sr += w.x * m[j];
                si += w.y * m[j];
            }
            float pr = sr * sr + si * si;
            z0 += (i & 8) ? -pr : pr;
            z1 += (i & 4) ? -pr : pr;
            z2 += (i & 2) ? -pr : pr;
            z3 += (i & 1) ? -pr : pr;
        }

        float l0 = fc_b[0] + fc_w[0]  * z0 + fc_w[1]  * z1 + fc_w[2]  * z2 + fc_w[3]  * z3;
        float l1 = fc_b[1] + fc_w[4]  * z0 + fc_w[5]  * z1 + fc_w[6]  * z2 + fc_w[7]  * z3;
        float l2 = fc_b[2] + fc_w[8]  * z0 + fc_w[9]  * z1 + fc_w[10] * z2 + fc_w[11] * z3;
        float l3 = fc_b[3] + fc_w[12] * z0 + fc_w[13] * z1 + fc_w[14] * z2 + fc_w[15] * z3;
        out[(size_t)blockIdx.x * IMGS1 + tid] = make_float4(l0, l1, l2, l3);

        // BN partials over the 64 images (wave 0)
        float s[8] = { l0, l1, l2, l3, l0 * l0, l1 * l1, l2 * l2, l3 * l3 };
#pragma unroll
        for (int off = 32; off; off >>= 1) {
#pragma unroll
            for (int q2 = 0; q2 < 8; ++q2) s[q2] += __shfl_down(s[q2], off);
        }
        if (tid == 0) {
            float4* p = (float4*)(partial + (size_t)blockIdx.x * 8);
            p[0] = make_float4(s[0], s[1], s[2], s[3]);
            p[1] = make_float4(s[4], s[5], s[6], s[7]);
        }
    }
}

// ---------------------------------------------------------------------------
// Finalize: each of 256 blocks redundantly reduces the 1024x8 partials
// (L2-hit), computes scale/shift, normalizes its 256 images in place.
// ---------------------------------------------------------------------------
__global__ __launch_bounds__(256) void finalize_kernel(
        float4* __restrict__ out,
        const float* __restrict__ partial,   // [NBLK1][8]
        const float* __restrict__ gamma,
        const float* __restrict__ beta) {
    __shared__ float red4[4][8];
    __shared__ float scsh[8];
    const int tid = threadIdx.x;

    float s[8];
#pragma unroll
    for (int q = 0; q < 8; ++q) s[q] = 0.f;
#pragma unroll
    for (int r = 0; r < NBLK1 / 256; ++r) {
        const float4* row = (const float4*)(partial + (size_t)(tid + r * 256) * 8);
        float4 a = row[0], c = row[1];
        s[0] += a.x; s[1] += a.y; s[2] += a.z; s[3] += a.w;
        s[4] += c.x; s[5] += c.y; s[6] += c.z; s[7] += c.w;
    }
#pragma unroll
    for (int off = 32; off; off >>= 1) {
#pragma unroll
        for (int q = 0; q < 8; ++q) s[q] += __shfl_down(s[q], off);
    }
    if ((tid & 63) == 0) {
#pragma unroll
        for (int q = 0; q < 8; ++q) red4[tid >> 6][q] = s[q];
    }
    __syncthreads();
    if (tid < 8) {
        red4[0][tid] = red4[0][tid] + red4[1][tid] + red4[2][tid] + red4[3][tid];
    }
    __syncthreads();
    if (tid < 4) {
        const float invB = 1.0f / (float)NB;
        float mean = red4[0][tid] * invB;
        float var  = red4[0][4 + tid] * invB - mean * mean;
        float inv  = rsqrtf(var + 1e-5f);
        float g = gamma[tid];
        scsh[tid]     = g * inv;
        scsh[4 + tid] = beta[tid] - mean * g * inv;
    }
    __syncthreads();

    const float sc0 = scsh[0], sc1 = scsh[1], sc2 = scsh[2], sc3 = scsh[3];
    const float sh0 = scsh[4], sh1 = scsh[5], sh2 = scsh[6], sh3 = scsh[7];
    const int b = blockIdx.x * 256 + tid;    // 256 blocks cover NB
    float4 v = out[b];
    v.x = v.x * sc0 + sh0;
    v.y = v.y * sc1 + sh1;
    v.z = v.z * sc2 + sh2;
    v.w = v.w * sc3 + sh3;
    out[b] = v;
}

// ---------------------------------------------------------------------------
extern "C" void kernel_launch(void* const* d_in, const int* in_sizes, int n_in,
                              void* d_out, int out_size, void* d_ws, size_t ws_size,
                              hipStream_t stream) {
    const float* x       = (const float*)d_in[0];
    const float* pre_w   = (const float*)d_in[1];
    const float* pre_b   = (const float*)d_in[2];
    const float* weights = (const float*)d_in[3];
    const float* fc_w    = (const float*)d_in[4];
    const float* fc_b    = (const float*)d_in[5];
    const float* gamma   = (const float*)d_in[6];
    const float* beta    = (const float*)d_in[7];

    float* partial = (float*)d_ws;           // NBLK1*8*4 = 32 KB

    hipLaunchKernelGGL(fused_kernel, dim3(NBLK1), dim3(256), 0, stream,
                       x, pre_w, pre_b, weights, fc_w, fc_b,
                       (float4*)d_out, partial);
    hipLaunchKernelGGL(finalize_kernel, dim3(NB / 256), dim3(256), 0, stream,
                       (float4*)d_out, partial, gamma, beta);
}

// Round 9
// 41.423 us; speedup vs baseline: 2.9693x; 1.1313x over previous
//
#include <hip/hip_runtime.h>
#include <math.h>

#define NB 65536          // batch
#define NBLK1 2048        // fused grid: NB / IMGS1 (100% occupancy grid)
#define IMGS1 32          // images per block (8 threads/image, 3 rows each)

// ---------------------------------------------------------------------------
// Fused kernel: W-build (wave 3 lanes 0-15) + avg-pool 6x6 + pre-FC +
// quantum matvec + logits + per-block BN partials.
// 2048 blocks x 256 threads = 524288 threads = 32 waves/CU (100% occupancy
// at <=64 VGPR). Weights loaded AFTER pooling (R5 lesson: preloading them
// under a VGPR cap spills).
// ---------------------------------------------------------------------------
__global__ __launch_bounds__(256) void fused_kernel(
        const float* __restrict__ x,        // [B][1][28][28]
        const float* __restrict__ pre_w,    // [4][16]
        const float* __restrict__ pre_b,    // [4]
        const float* __restrict__ weights,  // [3][4][2]
        const float* __restrict__ fc_w,     // [4][4]
        const float* __restrict__ fc_b,     // [4]
        float4* __restrict__ out,           // [B] raw logits
        float* __restrict__ partial) {      // [NBLK1][8]
    __shared__ float2 Wl[256];
    __shared__ float4 enc[IMGS1];
    const int tid = threadIdx.x;

    // ---------------- build W on wave 3 lanes 0-15 -------------------------
    // (hidden under waves 0-2's pool loads; needed only after the barrier)
    if (tid >= 192 && tid < 208) {
        const int t = tid - 192;
        float cr[16], ci[16];
#pragma unroll
        for (int i = 0; i < 16; ++i) { cr[i] = (i == t) ? 1.0f : 0.0f; ci[i] = 0.0f; }

        for (int l = 0; l < 3; ++l) {
#pragma unroll
            for (int w = 0; w < 4; ++w) {
                const int mask = 8 >> w;            // wire w -> bit (3-w)
                float tx = weights[(l * 4 + w) * 2 + 0] * 0.5f;
                float c = cosf(tx), s = sinf(tx);
#pragma unroll
                for (int i = 0; i < 16; ++i) {
                    if (!(i & mask)) {
                        const int ip = i | mask;
                        float a0r = cr[i], a0i = ci[i], a1r = cr[ip], a1i = ci[ip];
                        cr[i]  = c * a0r + s * a1i;   // [[c,-is],[-is,c]]
                        ci[i]  = c * a0i - s * a1r;
                        cr[ip] = c * a1r + s * a0i;
                        ci[ip] = c * a1i - s * a0r;
                    }
                }
                float tz = weights[(l * 4 + w) * 2 + 1] * 0.5f;
                float ce = cosf(tz), se = sinf(tz);
#pragma unroll
                for (int i = 0; i < 16; ++i) {
                    if (!(i & mask)) {
                        const int ip = i | mask;
                        float a0r = cr[i], a0i = ci[i], a1r = cr[ip], a1i = ci[ip];
                        cr[i]  = ce * a0r + se * a0i;  // e^{-i tz}
                        ci[i]  = ce * a0i - se * a0r;
                        cr[ip] = ce * a1r - se * a1i;  // e^{+i tz}
                        ci[ip] = ce * a1i + se * a1r;
                    }
                }
            }
#pragma unroll
            for (int w = 0; w < 4; ++w) {           // CNOT ring
                const int mc = 8 >> w;
                const int mt = 8 >> ((w + 1) & 3);
#pragma unroll
                for (int i = 0; i < 16; ++i) {
                    if ((i & mc) && !(i & mt)) {
                        const int ip = i | mt;
                        float tr = cr[i], ti = ci[i];
                        cr[i] = cr[ip]; ci[i] = ci[ip];
                        cr[ip] = tr;   ci[ip] = ti;
                    }
                }
            }
        }
        int p = __popc(t) & 3;   // fold zeta_j = (-i)^popcount(j)
#pragma unroll
        for (int i = 0; i < 16; ++i) {
            float wr, wi;
            if (p == 0)      { wr =  cr[i]; wi =  ci[i]; }
            else if (p == 1) { wr =  ci[i]; wi = -cr[i]; }
            else if (p == 2) { wr = -cr[i]; wi = -ci[i]; }
            else             { wr = -ci[i]; wi =  cr[i]; }
            Wl[i * 16 + t] = make_float2(wr, wi);
        }
    }

    // ---------------- pool + pre-FC (8 threads/image, 3 rows each) ---------
    const int t8 = tid & 7;                         // row-band 3*t8..3*t8+2
    const size_t img_idx = (size_t)blockIdx.x * IMGS1 + (tid >> 3);
    const float* img = x + img_idx * 784 + (size_t)(t8 * 3) * 28;

    float cs0 = 0.f, cs1 = 0.f, cs2 = 0.f, cs3 = 0.f;
#pragma unroll
    for (int r = 0; r < 3; ++r) {
        const float4* row = (const float4*)(img + r * 28);  // 16B-aligned
        float4 f0 = row[0], f1 = row[1], f2 = row[2];
        float4 f3 = row[3], f4 = row[4], f5 = row[5];
        cs0 += f0.x + f0.y + f0.z + f0.w + f1.x + f1.y;   // cols 0..5
        cs1 += f1.z + f1.w + f2.x + f2.y + f2.z + f2.w;   // cols 6..11
        cs2 += f3.x + f3.y + f3.z + f3.w + f4.x + f4.y;   // cols 12..17
        cs3 += f4.z + f4.w + f5.x + f5.y + f5.z + f5.w;   // cols 18..23
    }
    const float inv36 = 1.0f / 36.0f;
    cs0 *= inv36; cs1 *= inv36; cs2 *= inv36; cs3 *= inv36;

    // pre-FC partials (weights loaded post-pool; k0 = 4 * vertical band)
    const int k0 = (t8 >> 1) * 4;
    float p0 = cs0 * pre_w[k0]      + cs1 * pre_w[k0 + 1] +
               cs2 * pre_w[k0 + 2]  + cs3 * pre_w[k0 + 3];
    float p1 = cs0 * pre_w[16 + k0] + cs1 * pre_w[16 + k0 + 1] +
               cs2 * pre_w[16 + k0 + 2] + cs3 * pre_w[16 + k0 + 3];
    float p2 = cs0 * pre_w[32 + k0] + cs1 * pre_w[32 + k0 + 1] +
               cs2 * pre_w[32 + k0 + 2] + cs3 * pre_w[32 + k0 + 3];
    float p3 = cs0 * pre_w[48 + k0] + cs1 * pre_w[48 + k0 + 1] +
               cs2 * pre_w[48 + k0 + 2] + cs3 * pre_w[48 + k0 + 3];

    // combine the 8 row-bands of one image (8-lane group)
    p0 += __shfl_xor(p0, 1); p0 += __shfl_xor(p0, 2); p0 += __shfl_xor(p0, 4);
    p1 += __shfl_xor(p1, 1); p1 += __shfl_xor(p1, 2); p1 += __shfl_xor(p1, 4);
    p2 += __shfl_xor(p2, 1); p2 += __shfl_xor(p2, 2); p2 += __shfl_xor(p2, 4);
    p3 += __shfl_xor(p3, 1); p3 += __shfl_xor(p3, 2); p3 += __shfl_xor(p3, 4);

    if (t8 == 0) {
        enc[tid >> 3] = make_float4(p0 + pre_b[0], p1 + pre_b[1],
                                    p2 + pre_b[2], p3 + pre_b[3]);
    }
    __syncthreads();

    // ---------------- quantum matvec + logits (lanes 0-31 of wave 0) -------
    if (tid < IMGS1) {
        float4 e = enc[tid];
        float s0, c0, s1, c1, s2, c2, s3, c3;
        __sincosf(e.x * 0.5f, &s0, &c0);
        __sincosf(e.y * 0.5f, &s1, &c1);
        __sincosf(e.z * 0.5f, &s2, &c2);
        __sincosf(e.w * 0.5f, &s3, &c3);

        float m01[4] = { c0 * c1, c0 * s1, s0 * c1, s0 * s1 };
        float m23[4] = { c2 * c3, c2 * s3, s2 * c3, s2 * s3 };
        float m[16];
#pragma unroll
        for (int i = 0; i < 16; ++i) m[i] = m01[i >> 2] * m23[i & 3];

        float z0 = 0.f, z1 = 0.f, z2 = 0.f, z3 = 0.f;
#pragma unroll
        for (int i = 0; i < 16; ++i) {
            float sr = 0.f, si = 0.f;
#pragma unroll
            for (int j = 0; j < 16; ++j) {
                float2 w = Wl[i * 16 + j];   // wave-uniform -> LDS broadcast
                sr += w.x * m[j];
                si += w.y * m[j];
            }
            float pr = sr * sr + si * si;
            z0 += (i & 8) ? -pr : pr;
            z1 += (i & 4) ? -pr : pr;
            z2 += (i & 2) ? -pr : pr;
            z3 += (i & 1) ? -pr : pr;
        }

        float l0 = fc_b[0] + fc_w[0]  * z0 + fc_w[1]  * z1 + fc_w[2]  * z2 + fc_w[3]  * z3;
        float l1 = fc_b[1] + fc_w[4]  * z0 + fc_w[5]  * z1 + fc_w[6]  * z2 + fc_w[7]  * z3;
        float l2 = fc_b[2] + fc_w[8]  * z0 + fc_w[9]  * z1 + fc_w[10] * z2 + fc_w[11] * z3;
        float l3 = fc_b[3] + fc_w[12] * z0 + fc_w[13] * z1 + fc_w[14] * z2 + fc_w[15] * z3;
        out[(size_t)blockIdx.x * IMGS1 + tid] = make_float4(l0, l1, l2, l3);

        // BN partials over the 32 images (lanes 0-31)
        float s[8] = { l0, l1, l2, l3, l0 * l0, l1 * l1, l2 * l2, l3 * l3 };
#pragma unroll
        for (int off = 16; off; off >>= 1) {
#pragma unroll
            for (int q = 0; q < 8; ++q) s[q] += __shfl_down(s[q], off);
        }
        if (tid == 0) {
            float4* p = (float4*)(partial + (size_t)blockIdx.x * 8);
            p[0] = make_float4(s[0], s[1], s[2], s[3]);
            p[1] = make_float4(s[4], s[5], s[6], s[7]);
        }
    }
}

// ---------------------------------------------------------------------------
// Finalize: each of 256 blocks redundantly reduces the 2048x8 partials
// (L2-hit), computes scale/shift, normalizes its 256 images in place.
// ---------------------------------------------------------------------------
__global__ __launch_bounds__(256) void finalize_kernel(
        float4* __restrict__ out,
        const float* __restrict__ partial,   // [NBLK1][8]
        const float* __restrict__ gamma,
        const float* __restrict__ beta) {
    __shared__ float red4[4][8];
    __shared__ float scsh[8];
    const int tid = threadIdx.x;

    float s[8];
#pragma unroll
    for (int q = 0; q < 8; ++q) s[q] = 0.f;
#pragma unroll
    for (int r = 0; r < NBLK1 / 256; ++r) {
        const float4* row = (const float4*)(partial + (size_t)(tid + r * 256) * 8);
        float4 a = row[0], c = row[1];
        s[0] += a.x; s[1] += a.y; s[2] += a.z; s[3] += a.w;
        s[4] += c.x; s[5] += c.y; s[6] += c.z; s[7] += c.w;
    }
#pragma unroll
    for (int off = 32; off; off >>= 1) {
#pragma unroll
        for (int q = 0; q < 8; ++q) s[q] += __shfl_down(s[q], off);
    }
    if ((tid & 63) == 0) {
#pragma unroll
        for (int q = 0; q < 8; ++q) red4[tid >> 6][q] = s[q];
    }
    __syncthreads();
    if (tid < 8) {
        red4[0][tid] = red4[0][tid] + red4[1][tid] + red4[2][tid] + red4[3][tid];
    }
    __syncthreads();
    if (tid < 4) {
        const float invB = 1.0f / (float)NB;
        float mean = red4[0][tid] * invB;
        float var  = red4[0][4 + tid] * invB - mean * mean;
        float inv  = rsqrtf(var + 1e-5f);
        float g = gamma[tid];
        scsh[tid]     = g * inv;
        scsh[4 + tid] = beta[tid] - mean * g * inv;
    }
    __syncthreads();

    const float sc0 = scsh[0], sc1 = scsh[1], sc2 = scsh[2], sc3 = scsh[3];
    const float sh0 = scsh[4], sh1 = scsh[5], sh2 = scsh[6], sh3 = scsh[7];
    const int b = blockIdx.x * 256 + tid;    // 256 blocks cover NB
    float4 v = out[b];
    v.x = v.x * sc0 + sh0;
    v.y = v.y * sc1 + sh1;
    v.z = v.z * sc2 + sh2;
    v.w = v.w * sc3 + sh3;
    out[b] = v;
}

// ---------------------------------------------------------------------------
extern "C" void kernel_launch(void* const* d_in, const int* in_sizes, int n_in,
                              void* d_out, int out_size, void* d_ws, size_t ws_size,
                              hipStream_t stream) {
    const float* x       = (const float*)d_in[0];
    const float* pre_w   = (const float*)d_in[1];
    const float* pre_b   = (const float*)d_in[2];
    const float* weights = (const float*)d_in[3];
    const float* fc_w    = (const float*)d_in[4];
    const float* fc_b    = (const float*)d_in[5];
    const float* gamma   = (const float*)d_in[6];
    const float* beta    = (const float*)d_in[7];

    float* partial = (float*)d_ws;           // NBLK1*8*4 = 64 KB

    hipLaunchKernelGGL(fused_kernel, dim3(NBLK1), dim3(256), 0, stream,
                       x, pre_w, pre_b, weights, fc_w, fc_b,
                       (float4*)d_out, partial);
    hipLaunchKernelGGL(finalize_kernel, dim3(NB / 256), dim3(256), 0, stream,
                       (float4*)d_out, partial, gamma, beta);
}